// Round 7
// baseline (454.055 us; speedup 1.0000x reference)
//
#include <hip/hip_runtime.h>
#include <hip/hip_bf16.h>

#define DM   768
#define NH   12
#define HD   64
#define NTOK 1024
#define FFD  3072

typedef __bf16 bf16x8 __attribute__((ext_vector_type(8)));
typedef __attribute__((ext_vector_type(4))) float f32x4;

#define MFMA16(a, b, c) __builtin_amdgcn_mfma_f32_16x16x32_bf16(a, b, c, 0, 0, 0)

__device__ inline ushort f2bf(float f) {
  union { float f; uint u; } v; v.f = f;
  uint u = v.u;
  uint r = (u + 0x7FFFu + ((u >> 16) & 1u)) >> 16;
  return (ushort)r;
}
__device__ inline float bf2f(ushort h) {
  union { uint u; float f; } v; v.u = ((uint)h) << 16;
  return v.f;
}

// bijective XCD chunk swizzle (m204)
__device__ inline int xcd_swz(int b, int nwg) {
  int q = nwg >> 3, r = nwg & 7;
  int x = b & 7, i = b >> 3;
  return (x < r) ? x * (q + 1) + i : r * (q + 1) + (x - r) * q + i;
}

// ---------------- fp32 -> bf16 weight conversion ----------------
__global__ void cvt_kernel(const float* __restrict__ in, ushort* __restrict__ out, int n4) {
  int i = blockIdx.x * blockDim.x + threadIdx.x;
  int stride = gridDim.x * blockDim.x;
  for (; i < n4; i += stride) {
    float4 v = ((const float4*)in)[i];
    ushort4 o;
    o.x = f2bf(v.x); o.y = f2bf(v.y); o.z = f2bf(v.z); o.w = f2bf(v.w);
    ((ushort4*)out)[i] = o;
  }
}

// ---------------- RMSNorm (one block per row) ----------------
__global__ __launch_bounds__(256) void rmsnorm_kernel(
    const float* __restrict__ x, const float* __restrict__ w,
    ushort* __restrict__ outB, float* __restrict__ outF) {
  int row = blockIdx.x;
  const float* xr = x + row * DM;
  int tid = threadIdx.x;
  float v0 = xr[tid], v1 = xr[tid + 256], v2 = xr[tid + 512];
  float ss = v0 * v0 + v1 * v1 + v2 * v2;
  for (int off = 32; off; off >>= 1) ss += __shfl_xor(ss, off, 64);
  __shared__ float red[4];
  int wid = tid >> 6;
  if ((tid & 63) == 0) red[wid] = ss;
  __syncthreads();
  float tot = red[0] + red[1] + red[2] + red[3];
  float scale = rsqrtf(tot * (1.0f / DM) + 1e-6f);
  float o0 = v0 * scale * w[tid];
  float o1 = v1 * scale * w[tid + 256];
  float o2 = v2 * scale * w[tid + 512];
  if (outB) {
    outB[row * DM + tid]       = f2bf(o0);
    outB[row * DM + tid + 256] = f2bf(o1);
    outB[row * DM + tid + 512] = f2bf(o2);
  } else {
    outF[row * DM + tid]       = o0;
    outF[row * DM + tid + 256] = o1;
    outF[row * DM + tid + 512] = o2;
  }
}

// ---------------- bf16 MFMA GEMM: 64x64 block (2 waves), split-K ----------------
// out mode: outP (plain fp32 partial at ks*M*N) | outF (atomicAdd fp32) | outB (bf16, S==1)
__global__ __launch_bounds__(128) void gemm_k(
    const ushort* __restrict__ A, const ushort* __restrict__ B,
    const float* __restrict__ bias,
    float* __restrict__ outP, float* __restrict__ outF, ushort* __restrict__ outB,
    int M, int N, int K, int S) {
  int tile = xcd_swz(blockIdx.x, gridDim.x);
  int MB = M >> 6;
  int mblk = tile % MB, nblk = tile / MB;
  int m0 = mblk * 64, n0 = nblk * 64;
  int ks = blockIdx.y;
  int lane = threadIdx.x & 63, wid = threadIdx.x >> 6;
  int r = lane & 15, kg = lane >> 4;
  int Ks = K / S, k0 = ks * Ks;
  int nsteps = Ks >> 5;

  const ushort* Ab = A + (size_t)(m0 + wid * 32 + r) * K + kg * 8 + k0;
  const ushort* Bb = B + (size_t)(n0 + r) * K + kg * 8 + k0;

  f32x4 acc[2][4] = {};
  bf16x8 a0 = *(const bf16x8*)(Ab);
  bf16x8 a1 = *(const bf16x8*)(Ab + 16 * K);
  bf16x8 b0 = *(const bf16x8*)(Bb);
  bf16x8 b1 = *(const bf16x8*)(Bb + 16 * K);
  bf16x8 b2 = *(const bf16x8*)(Bb + 32 * K);
  bf16x8 b3 = *(const bf16x8*)(Bb + 48 * K);

  for (int s = 1; s < nsteps; ++s) {
    const ushort* An = Ab + s * 32;
    const ushort* Bn = Bb + s * 32;
    bf16x8 na0 = *(const bf16x8*)(An);
    bf16x8 na1 = *(const bf16x8*)(An + 16 * K);
    bf16x8 nb0 = *(const bf16x8*)(Bn);
    bf16x8 nb1 = *(const bf16x8*)(Bn + 16 * K);
    bf16x8 nb2 = *(const bf16x8*)(Bn + 32 * K);
    bf16x8 nb3 = *(const bf16x8*)(Bn + 48 * K);
    acc[0][0] = MFMA16(a0, b0, acc[0][0]);
    acc[0][1] = MFMA16(a0, b1, acc[0][1]);
    acc[0][2] = MFMA16(a0, b2, acc[0][2]);
    acc[0][3] = MFMA16(a0, b3, acc[0][3]);
    acc[1][0] = MFMA16(a1, b0, acc[1][0]);
    acc[1][1] = MFMA16(a1, b1, acc[1][1]);
    acc[1][2] = MFMA16(a1, b2, acc[1][2]);
    acc[1][3] = MFMA16(a1, b3, acc[1][3]);
    a0 = na0; a1 = na1; b0 = nb0; b1 = nb1; b2 = nb2; b3 = nb3;
  }
  acc[0][0] = MFMA16(a0, b0, acc[0][0]);
  acc[0][1] = MFMA16(a0, b1, acc[0][1]);
  acc[0][2] = MFMA16(a0, b2, acc[0][2]);
  acc[0][3] = MFMA16(a0, b3, acc[0][3]);
  acc[1][0] = MFMA16(a1, b0, acc[1][0]);
  acc[1][1] = MFMA16(a1, b1, acc[1][1]);
  acc[1][2] = MFMA16(a1, b2, acc[1][2]);
  acc[1][3] = MFMA16(a1, b3, acc[1][3]);

  int crow = m0 + wid * 32 + kg * 4;
  int ccol = n0 + r;
  float* po = outP ? outP + (size_t)ks * M * N : nullptr;
#pragma unroll
  for (int mi = 0; mi < 2; ++mi)
#pragma unroll
    for (int ni = 0; ni < 4; ++ni) {
      int col = ccol + ni * 16;
      float bv = (bias && ks == 0) ? bias[col] : 0.0f;
#pragma unroll
      for (int q = 0; q < 4; ++q) {
        int row = crow + mi * 16 + q;
        size_t idx = (size_t)row * N + col;
        float val = acc[mi][ni][q] + bv;
        if (po)        po[idx] = val;
        else if (outF) atomicAdd(outF + idx, val);
        else           outB[idx] = f2bf(val);
      }
    }
}

// ---------------- FFN-up GEMMs: partial fp32 acc1/acc3 (silu deferred) ----------------
__global__ __launch_bounds__(128) void gemm_ffn(
    const ushort* __restrict__ A, const ushort* __restrict__ B1,
    const ushort* __restrict__ B3, float* __restrict__ h1P, float* __restrict__ h3P,
    int S) {
  const int K = DM, N = FFD, M = NTOK;
  int tile = xcd_swz(blockIdx.x, gridDim.x);
  int MB = M >> 6;
  int mblk = tile % MB, nblk = tile / MB;
  int m0 = mblk * 64, n0 = nblk * 64;
  int ks = blockIdx.y;
  int lane = threadIdx.x & 63, wid = threadIdx.x >> 6;
  int r = lane & 15, kg = lane >> 4;
  int Ks = K / S, k0 = ks * Ks;
  int nsteps = Ks >> 5;

  const ushort* Ab  = A  + (size_t)(m0 + wid * 32 + r) * K + kg * 8 + k0;
  const ushort* B1b = B1 + (size_t)(n0 + r) * K + kg * 8 + k0;
  const ushort* B3b = B3 + (size_t)(n0 + r) * K + kg * 8 + k0;

  f32x4 acc1[2][4] = {};
  f32x4 acc3[2][4] = {};
  bf16x8 a0 = *(const bf16x8*)(Ab);
  bf16x8 a1 = *(const bf16x8*)(Ab + 16 * K);
  bf16x8 p0 = *(const bf16x8*)(B1b);
  bf16x8 p1 = *(const bf16x8*)(B1b + 16 * K);
  bf16x8 p2 = *(const bf16x8*)(B1b + 32 * K);
  bf16x8 p3 = *(const bf16x8*)(B1b + 48 * K);
  bf16x8 t0 = *(const bf16x8*)(B3b);
  bf16x8 t1 = *(const bf16x8*)(B3b + 16 * K);
  bf16x8 t2 = *(const bf16x8*)(B3b + 32 * K);
  bf16x8 t3 = *(const bf16x8*)(B3b + 48 * K);

  for (int s = 1; s < nsteps; ++s) {
    const ushort* An = Ab + s * 32;
    const ushort* Pn = B1b + s * 32;
    const ushort* Tn = B3b + s * 32;
    bf16x8 na0 = *(const bf16x8*)(An);
    bf16x8 na1 = *(const bf16x8*)(An + 16 * K);
    bf16x8 np0 = *(const bf16x8*)(Pn);
    bf16x8 np1 = *(const bf16x8*)(Pn + 16 * K);
    bf16x8 np2 = *(const bf16x8*)(Pn + 32 * K);
    bf16x8 np3 = *(const bf16x8*)(Pn + 48 * K);
    bf16x8 nt0 = *(const bf16x8*)(Tn);
    bf16x8 nt1 = *(const bf16x8*)(Tn + 16 * K);
    bf16x8 nt2 = *(const bf16x8*)(Tn + 32 * K);
    bf16x8 nt3 = *(const bf16x8*)(Tn + 48 * K);
    acc1[0][0] = MFMA16(a0, p0, acc1[0][0]);
    acc1[0][1] = MFMA16(a0, p1, acc1[0][1]);
    acc1[0][2] = MFMA16(a0, p2, acc1[0][2]);
    acc1[0][3] = MFMA16(a0, p3, acc1[0][3]);
    acc1[1][0] = MFMA16(a1, p0, acc1[1][0]);
    acc1[1][1] = MFMA16(a1, p1, acc1[1][1]);
    acc1[1][2] = MFMA16(a1, p2, acc1[1][2]);
    acc1[1][3] = MFMA16(a1, p3, acc1[1][3]);
    acc3[0][0] = MFMA16(a0, t0, acc3[0][0]);
    acc3[0][1] = MFMA16(a0, t1, acc3[0][1]);
    acc3[0][2] = MFMA16(a0, t2, acc3[0][2]);
    acc3[0][3] = MFMA16(a0, t3, acc3[0][3]);
    acc3[1][0] = MFMA16(a1, t0, acc3[1][0]);
    acc3[1][1] = MFMA16(a1, t1, acc3[1][1]);
    acc3[1][2] = MFMA16(a1, t2, acc3[1][2]);
    acc3[1][3] = MFMA16(a1, t3, acc3[1][3]);
    a0 = na0; a1 = na1;
    p0 = np0; p1 = np1; p2 = np2; p3 = np3;
    t0 = nt0; t1 = nt1; t2 = nt2; t3 = nt3;
  }
  acc1[0][0] = MFMA16(a0, p0, acc1[0][0]);
  acc1[0][1] = MFMA16(a0, p1, acc1[0][1]);
  acc1[0][2] = MFMA16(a0, p2, acc1[0][2]);
  acc1[0][3] = MFMA16(a0, p3, acc1[0][3]);
  acc1[1][0] = MFMA16(a1, p0, acc1[1][0]);
  acc1[1][1] = MFMA16(a1, p1, acc1[1][1]);
  acc1[1][2] = MFMA16(a1, p2, acc1[1][2]);
  acc1[1][3] = MFMA16(a1, p3, acc1[1][3]);
  acc3[0][0] = MFMA16(a0, t0, acc3[0][0]);
  acc3[0][1] = MFMA16(a0, t1, acc3[0][1]);
  acc3[0][2] = MFMA16(a0, t2, acc3[0][2]);
  acc3[0][3] = MFMA16(a0, t3, acc3[0][3]);
  acc3[1][0] = MFMA16(a1, t0, acc3[1][0]);
  acc3[1][1] = MFMA16(a1, t1, acc3[1][1]);
  acc3[1][2] = MFMA16(a1, t2, acc3[1][2]);
  acc3[1][3] = MFMA16(a1, t3, acc3[1][3]);

  int crow = m0 + wid * 32 + kg * 4;
  int ccol = n0 + r;
  size_t kof = (size_t)ks * M * N;
#pragma unroll
  for (int mi = 0; mi < 2; ++mi)
#pragma unroll
    for (int ni = 0; ni < 4; ++ni)
#pragma unroll
      for (int q = 0; q < 4; ++q) {
        int row = crow + mi * 16 + q;
        int col = ccol + ni * 16;
        size_t idx = kof + (size_t)row * N + col;
        h1P[idx] = acc1[mi][ni][q];
        h3P[idx] = acc3[mi][ni][q];
      }
}

// ---------------- finisher: qkvb = bf16(p0 + p1) ----------------
__global__ __launch_bounds__(256) void add2_kernel(
    const float* __restrict__ p0, const float* __restrict__ p1,
    ushort* __restrict__ out, int n4) {
  int i = blockIdx.x * blockDim.x + threadIdx.x;
  int stride = gridDim.x * blockDim.x;
  for (; i < n4; i += stride) {
    float4 a = ((const float4*)p0)[i];
    float4 b = ((const float4*)p1)[i];
    ushort4 o;
    o.x = f2bf(a.x + b.x); o.y = f2bf(a.y + b.y);
    o.z = f2bf(a.z + b.z); o.w = f2bf(a.w + b.w);
    ((ushort4*)out)[i] = o;
  }
}

// ---------------- finisher: hg = silu(h1a+h1b) * (h3a+h3b) ----------------
__global__ __launch_bounds__(256) void swiglu2_kernel(
    const float* __restrict__ h1a, const float* __restrict__ h1b,
    const float* __restrict__ h3a, const float* __restrict__ h3b,
    ushort* __restrict__ hg, int n4) {
  int i = blockIdx.x * blockDim.x + threadIdx.x;
  int stride = gridDim.x * blockDim.x;
  for (; i < n4; i += stride) {
    float4 a = ((const float4*)h1a)[i];
    float4 b = ((const float4*)h1b)[i];
    float4 c = ((const float4*)h3a)[i];
    float4 d = ((const float4*)h3b)[i];
    float g0 = a.x + b.x, g1 = a.y + b.y, g2 = a.z + b.z, g3 = a.w + b.w;
    ushort4 o;
    o.x = f2bf(g0 / (1.0f + __expf(-g0)) * (c.x + d.x));
    o.y = f2bf(g1 / (1.0f + __expf(-g1)) * (c.y + d.y));
    o.z = f2bf(g2 / (1.0f + __expf(-g2)) * (c.z + d.z));
    o.w = f2bf(g3 / (1.0f + __expf(-g3)) * (c.w + d.w));
    ((ushort4*)hg)[i] = o;
  }
}

// ---------------- 3D neighborhood attention: block per (t, h, head) ----------------
__global__ __launch_bounds__(256) void attn_kernel(
    const ushort* __restrict__ qkv, ushort* __restrict__ out) {
  int head = blockIdx.x;
  int h    = blockIdx.y;
  int t    = blockIdx.z;
  int NT = (t + 1) * 5;                 // 16-key tiles
  int tid = threadIdx.x;
  int lane = tid & 63, wid = tid >> 6;
  int hstart = h - 2; hstart = hstart < 0 ? 0 : (hstart > 11 ? 11 : hstart);

  __shared__ ushort v_s[320 * 64];      // [j][d], bf16
  __shared__ ushort p_c[16][128];       // compressed P, bf16
  __shared__ float red_m[4][16], red_s[4][16];

  for (int c = tid; c < NT * 128; c += 256) {
    int j = c >> 3, dc = c & 7;
    int tile = j >> 4;
    int tp = tile / 5, hh = tile - tp * 5;
    int nb = tp * 256 + (hstart + hh) * 16 + (j & 15);
    uint4 v = *(const uint4*)(qkv + (size_t)nb * 2304 + 1536 + head * 64 + dc * 8);
    *(uint4*)(v_s + j * 64 + dc * 8) = v;
  }

  int c16 = lane & 15, kg = lane >> 4;
  const ushort* qp = qkv + (size_t)(t * 256 + h * 16 + c16) * 2304 + head * 64 + kg * 8;
  bf16x8 qa0 = *(const bf16x8*)qp;
  bf16x8 qa1 = *(const bf16x8*)(qp + 32);

  f32x4 acc[5];
#pragma unroll
  for (int s = 0; s < 5; ++s) {
    f32x4 a = {};
    int ti = wid + s * 4;
    if (ti < NT) {
      int tp = ti / 5, hh = ti - tp * 5;
      const ushort* kp = qkv + (size_t)(tp * 256 + (hstart + hh) * 16 + c16) * 2304
                         + 768 + head * 64 + kg * 8;
      bf16x8 b0 = *(const bf16x8*)kp;
      bf16x8 b1 = *(const bf16x8*)(kp + 32);
      a = __builtin_amdgcn_mfma_f32_16x16x32_bf16(qa0, b0, a, 0, 0, 0);
      a = __builtin_amdgcn_mfma_f32_16x16x32_bf16(qa1, b1, a, 0, 0, 0);
    }
    acc[s] = a;
  }

  bool valid[4]; int wst[4];
#pragma unroll
  for (int r = 0; r < 4; ++r) {
    int q = kg * 4 + r;
    int ws = q - 2; ws = ws < 0 ? 0 : (ws > 11 ? 11 : ws);
    wst[r] = ws;
    valid[r] = (c16 >= ws) && (c16 < ws + 5);
  }

  float mloc[4];
#pragma unroll
  for (int r = 0; r < 4; ++r) mloc[r] = -1e30f;
#pragma unroll
  for (int s = 0; s < 5; ++s) {
    if (wid + s * 4 < NT) {
#pragma unroll
      for (int r = 0; r < 4; ++r)
        if (valid[r]) mloc[r] = fmaxf(mloc[r], acc[s][r]);
    }
  }
#pragma unroll
  for (int r = 0; r < 4; ++r)
    for (int off = 8; off; off >>= 1) mloc[r] = fmaxf(mloc[r], __shfl_xor(mloc[r], off, 64));
  if (c16 == 0) {
#pragma unroll
    for (int r = 0; r < 4; ++r) red_m[wid][kg * 4 + r] = mloc[r];
  }
  __syncthreads();

  float mq[4];
#pragma unroll
  for (int r = 0; r < 4; ++r) {
    int q = kg * 4 + r;
    mq[r] = fmaxf(fmaxf(red_m[0][q], red_m[1][q]), fmaxf(red_m[2][q], red_m[3][q]));
  }

  float pv[5][4];
  float ssum[4] = {0.f, 0.f, 0.f, 0.f};
#pragma unroll
  for (int s = 0; s < 5; ++s) {
    bool live = (wid + s * 4 < NT);
#pragma unroll
    for (int r = 0; r < 4; ++r) {
      float p = (live && valid[r]) ? __expf((acc[s][r] - mq[r]) * 0.125f) : 0.0f;
      pv[s][r] = p;
      ssum[r] += p;
    }
  }
#pragma unroll
  for (int r = 0; r < 4; ++r)
    for (int off = 8; off; off >>= 1) ssum[r] += __shfl_xor(ssum[r], off, 64);
  if (c16 == 0) {
#pragma unroll
    for (int r = 0; r < 4; ++r) red_s[wid][kg * 4 + r] = ssum[r];
  }
  __syncthreads();

  float inv[4];
#pragma unroll
  for (int r = 0; r < 4; ++r) {
    int q = kg * 4 + r;
    inv[r] = 1.0f / (red_s[0][q] + red_s[1][q] + red_s[2][q] + red_s[3][q]);
  }

#pragma unroll
  for (int s = 0; s < 5; ++s) {
    int ti = wid + s * 4;
    if (ti < NT) {
      int tp = ti / 5, hh = ti - tp * 5;
#pragma unroll
      for (int r = 0; r < 4; ++r) {
        if (valid[r]) {
          int wc = c16 - wst[r];
          p_c[kg * 4 + r][(tp * 5 + hh) * 5 + wc] = f2bf(pv[s][r] * inv[r]);
        }
      }
    }
  }
  __syncthreads();

  int q  = tid >> 4;
  int dg = tid & 15;
  int ws2 = q - 2; ws2 = ws2 < 0 ? 0 : (ws2 > 11 ? 11 : ws2);
  float ox = 0.f, oy = 0.f, oz = 0.f, ow = 0.f;
  for (int tp = 0; tp <= t; ++tp) {
#pragma unroll
    for (int hh = 0; hh < 5; ++hh) {
      int jbase = tp * 80 + hh * 16 + ws2;
      const ushort* pb = &p_c[q][(tp * 5 + hh) * 5];
#pragma unroll
      for (int ww = 0; ww < 5; ++ww) {
        float p = bf2f(pb[ww]);
        uint2 v = *(const uint2*)(v_s + (jbase + ww) * 64 + dg * 4);
        ox += p * bf2f((ushort)(v.x & 0xffff));
        oy += p * bf2f((ushort)(v.x >> 16));
        oz += p * bf2f((ushort)(v.y & 0xffff));
        ow += p * bf2f((ushort)(v.y >> 16));
      }
    }
  }
  ushort4 ov;
  ov.x = f2bf(ox); ov.y = f2bf(oy); ov.z = f2bf(oz); ov.w = f2bf(ow);
  *(ushort4*)(out + (size_t)(t * 256 + h * 16 + q) * DM + head * 64 + dg * 4) = ov;
}

extern "C" void kernel_launch(void* const* d_in, const int* in_sizes, int n_in,
                              void* d_out, int out_size, void* d_ws, size_t ws_size,
                              hipStream_t stream) {
  const float* x_in    = (const float*)d_in[0];
  const float* norm1_w = (const float*)d_in[4];
  const float* norm2_w = (const float*)d_in[5];
  const float* qkv_w   = (const float*)d_in[6];
  const float* qkv_b   = (const float*)d_in[7];
  const float* out_w   = (const float*)d_in[8];
  const float* out_b   = (const float*)d_in[9];
  const float* w1      = (const float*)d_in[10];
  const float* w3      = (const float*)d_in[11];
  const float* w2      = (const float*)d_in[12];
  const float* fnw     = (const float*)d_in[13];

  char* p = (char*)d_ws;
  auto alloc = [&](size_t bytes) {
    char* r = p;
    p += (bytes + 255) & ~(size_t)255;
    return r;
  };
  ushort* wq_bf = (ushort*)alloc((size_t)2 * 2304 * 768 * 2);
  ushort* wo_bf = (ushort*)alloc((size_t)2 * 768 * 768 * 2);
  ushort* w1_bf = (ushort*)alloc((size_t)2 * 3072 * 768 * 2);
  ushort* w3_bf = (ushort*)alloc((size_t)2 * 3072 * 768 * 2);
  ushort* w2_bf = (ushort*)alloc((size_t)2 * 768 * 3072 * 2);
  float*  x     = (float*)alloc((size_t)NTOK * DM * 4);
  ushort* xn    = (ushort*)alloc((size_t)NTOK * DM * 2);
  ushort* qkvb  = (ushort*)alloc((size_t)NTOK * 2304 * 2);
  ushort* attnb = (ushort*)alloc((size_t)NTOK * DM * 2);
  ushort* hg    = (ushort*)alloc((size_t)NTOK * FFD * 2);
  // union scratch: qkv partials (2*9.4MB) alias ffn partials (2*(12.6+12.6)MB)
  float*  scr   = (float*)alloc((size_t)4 * NTOK * FFD * 4);
  float*  qkvP  = scr;                               // 2 * NTOK*2304
  float*  h1P   = scr;                               // 2 * NTOK*FFD
  float*  h3P   = scr + (size_t)2 * NTOK * FFD;      // 2 * NTOK*FFD

  hipMemcpyAsync(x, x_in, (size_t)NTOK * DM * 4, hipMemcpyDeviceToDevice, stream);

  auto cvt = [&](const float* in, ushort* out, int n) {
    int n4 = n / 4;
    int blocks = (n4 + 255) / 256;
    if (blocks > 2048) blocks = 2048;
    cvt_kernel<<<blocks, 256, 0, stream>>>(in, out, n4);
  };
  cvt(qkv_w, wq_bf, 2 * 2304 * 768);
  cvt(out_w, wo_bf, 2 * 768 * 768);
  cvt(w1,    w1_bf, 2 * 3072 * 768);
  cvt(w3,    w3_bf, 2 * 3072 * 768);
  cvt(w2,    w2_bf, 2 * 768 * 3072);

  const int MB = NTOK / 64;  // 16
  for (int l = 0; l < 2; ++l) {
    rmsnorm_kernel<<<NTOK, 256, 0, stream>>>(x, norm1_w + l * DM, xn, nullptr);
    // QKV: N=2304, S=2 -> fp32 partials, then combine to bf16
    gemm_k<<<dim3(MB * (2304 / 64), 2), 128, 0, stream>>>(
        xn, wq_bf + (size_t)l * 2304 * 768, qkv_b + l * 2304,
        qkvP, nullptr, nullptr, NTOK, 2304, 768, 2);
    add2_kernel<<<1152, 256, 0, stream>>>(
        qkvP, qkvP + (size_t)NTOK * 2304, qkvb, NTOK * 2304 / 4);
    attn_kernel<<<dim3(NH, 16, 4), 256, 0, stream>>>(qkvb, attnb);
    // out-proj: N=768, S=2, atomic into x (holds resid)
    gemm_k<<<dim3(MB * (DM / 64), 2), 128, 0, stream>>>(
        attnb, wo_bf + (size_t)l * 768 * 768, out_b + l * DM,
        nullptr, x, nullptr, NTOK, DM, 768, 2);
    rmsnorm_kernel<<<NTOK, 256, 0, stream>>>(x, norm2_w + l * DM, xn, nullptr);
    // FFN-up: S=2 partials, then swiglu combine
    gemm_ffn<<<dim3(MB * (FFD / 64), 2), 128, 0, stream>>>(
        xn, w1_bf + (size_t)l * 3072 * 768, w3_bf + (size_t)l * 3072 * 768,
        h1P, h3P, 2);
    swiglu2_kernel<<<2048, 256, 0, stream>>>(
        h1P, h1P + (size_t)NTOK * FFD, h3P, h3P + (size_t)NTOK * FFD,
        hg, NTOK * FFD / 4);
    // w2: N=768, K=3072, S=4, atomic into x
    gemm_k<<<dim3(MB * (DM / 64), 4), 128, 0, stream>>>(
        hg, w2_bf + (size_t)l * 768 * 3072, nullptr,
        nullptr, x, nullptr, NTOK, DM, 3072, 4);
  }
  rmsnorm_kernel<<<NTOK, 256, 0, stream>>>(x, fnw, nullptr, (float*)d_out);
}

// Round 8
// 318.369 us; speedup vs baseline: 1.4262x; 1.4262x over previous
//
#include <hip/hip_runtime.h>
#include <hip/hip_bf16.h>

#define DM   768
#define NH   12
#define HD   64
#define NTOK 1024
#define FFD  3072

typedef __bf16 bf16x8 __attribute__((ext_vector_type(8)));
typedef __attribute__((ext_vector_type(4))) float f32x4;

#define MFMA16(a, b, c) __builtin_amdgcn_mfma_f32_16x16x32_bf16(a, b, c, 0, 0, 0)

__device__ inline ushort f2bf(float f) {
  union { float f; uint u; } v; v.f = f;
  uint u = v.u;
  uint r = (u + 0x7FFFu + ((u >> 16) & 1u)) >> 16;
  return (ushort)r;
}
__device__ inline float bf2f(ushort h) {
  union { uint u; float f; } v; v.u = ((uint)h) << 16;
  return v.f;
}

// bijective XCD chunk swizzle (m204)
__device__ inline int xcd_swz(int b, int nwg) {
  int q = nwg >> 3, r = nwg & 7;
  int x = b & 7, i = b >> 3;
  return (x < r) ? x * (q + 1) + i : r * (q + 1) + (x - r) * q + i;
}

// ---------------- fp32 -> bf16 weight conversion ----------------
__global__ void cvt_kernel(const float* __restrict__ in, ushort* __restrict__ out, int n4) {
  int i = blockIdx.x * blockDim.x + threadIdx.x;
  int stride = gridDim.x * blockDim.x;
  for (; i < n4; i += stride) {
    float4 v = ((const float4*)in)[i];
    ushort4 o;
    o.x = f2bf(v.x); o.y = f2bf(v.y); o.z = f2bf(v.z); o.w = f2bf(v.w);
    ((ushort4*)out)[i] = o;
  }
}

// ---------------- RMSNorm (one block per row) ----------------
__global__ __launch_bounds__(256) void rmsnorm_kernel(
    const float* __restrict__ x, const float* __restrict__ w,
    ushort* __restrict__ outB, float* __restrict__ outF) {
  int row = blockIdx.x;
  const float* xr = x + row * DM;
  int tid = threadIdx.x;
  float v0 = xr[tid], v1 = xr[tid + 256], v2 = xr[tid + 512];
  float ss = v0 * v0 + v1 * v1 + v2 * v2;
  for (int off = 32; off; off >>= 1) ss += __shfl_xor(ss, off, 64);
  __shared__ float red[4];
  int wid = tid >> 6;
  if ((tid & 63) == 0) red[wid] = ss;
  __syncthreads();
  float tot = red[0] + red[1] + red[2] + red[3];
  float scale = rsqrtf(tot * (1.0f / DM) + 1e-6f);
  float o0 = v0 * scale * w[tid];
  float o1 = v1 * scale * w[tid + 256];
  float o2 = v2 * scale * w[tid + 512];
  if (outB) {
    outB[row * DM + tid]       = f2bf(o0);
    outB[row * DM + tid + 256] = f2bf(o1);
    outB[row * DM + tid + 512] = f2bf(o2);
  } else {
    outF[row * DM + tid]       = o0;
    outF[row * DM + tid + 256] = o1;
    outF[row * DM + tid + 512] = o2;
  }
}

// ---------------- LDS-staged bf16 MFMA GEMM ----------------
// Block tile 128(M)x64(N), 256 thr (4 waves, wave tile 32x64), BK=64,
// double-buffered LDS staged via global_load_lds (width 16).
// XOR swizzle: LDS chunk (row, ch) holds global chunk ch^(row&7)
// (source pre-swizzled, read swizzled — involution, rule #21).
// out: outF != 0 -> atomicAdd fp32 (+bias at ks==0); else bf16 (+bias), S==1.
// M fixed = NTOK (mblk in [0,8)).
__global__ __launch_bounds__(256) void gemm128(
    const ushort* __restrict__ A, const ushort* __restrict__ B,
    const float* __restrict__ bias,
    float* __restrict__ outF, ushort* __restrict__ outB,
    int N, int K, int S) {
  __shared__ ushort lds[2][12288];   // per buf: A 128x64 (8192), B 64x64 (4096)
  int tile = xcd_swz(blockIdx.x, gridDim.x);
  int mblk = tile & 7, nblk = tile >> 3;
  int m0 = mblk * 128, n0 = nblk * 64;
  int ks = blockIdx.y;
  int Ks = K / S, kbase = ks * Ks;
  int nkb = Ks >> 6;

  int tid = threadIdx.x;
  int lane = tid & 63, w = tid >> 6;
  int r = lane & 15, kg = lane >> 4;

  auto stage = [&](int buf, int kb) {
    int kcol = kbase + kb * 64;
#pragma unroll
    for (int i = 0; i < 4; ++i) {          // A: 1024 chunks of 16B
      int c = tid + i * 256;
      int row = c >> 3, ch = c & 7;
      int chs = ch ^ (row & 7);
      const ushort* src = A + (size_t)(m0 + row) * K + kcol + chs * 8;
      __builtin_amdgcn_global_load_lds(
          (const __attribute__((address_space(1))) uint*)src,
          (__attribute__((address_space(3))) uint*)&lds[buf][c * 8], 16, 0, 0);
    }
#pragma unroll
    for (int i = 0; i < 2; ++i) {          // B: 512 chunks of 16B
      int c = tid + i * 256;
      int row = c >> 3, ch = c & 7;
      int chs = ch ^ (row & 7);
      const ushort* src = B + (size_t)(n0 + row) * K + kcol + chs * 8;
      __builtin_amdgcn_global_load_lds(
          (const __attribute__((address_space(1))) uint*)src,
          (__attribute__((address_space(3))) uint*)&lds[buf][8192 + c * 8], 16, 0, 0);
    }
  };

  stage(0, 0);
  __syncthreads();

  f32x4 acc[2][4] = {};
  for (int kb = 0; kb < nkb; ++kb) {
    int buf = kb & 1;
    if (kb + 1 < nkb) stage(buf ^ 1, kb + 1);
    const ushort* Ar = &lds[buf][0];
    const ushort* Br = &lds[buf][8192];
#pragma unroll
    for (int s = 0; s < 2; ++s) {
      bf16x8 a[2], b[4];
#pragma unroll
      for (int mi = 0; mi < 2; ++mi) {
        int row = w * 32 + mi * 16 + r;
        int ch = (s * 4 + kg) ^ (row & 7);
        a[mi] = *(const bf16x8*)(Ar + row * 64 + ch * 8);
      }
#pragma unroll
      for (int ni = 0; ni < 4; ++ni) {
        int row = ni * 16 + r;
        int ch = (s * 4 + kg) ^ (row & 7);
        b[ni] = *(const bf16x8*)(Br + row * 64 + ch * 8);
      }
#pragma unroll
      for (int mi = 0; mi < 2; ++mi)
#pragma unroll
        for (int ni = 0; ni < 4; ++ni)
          acc[mi][ni] = MFMA16(a[mi], b[ni], acc[mi][ni]);
    }
    __syncthreads();
  }

  int crow = m0 + w * 32 + kg * 4;
  int ccol = n0 + r;
#pragma unroll
  for (int mi = 0; mi < 2; ++mi)
#pragma unroll
    for (int ni = 0; ni < 4; ++ni) {
      int col = ccol + ni * 16;
      float bv = (bias && ks == 0) ? bias[col] : 0.0f;
#pragma unroll
      for (int q = 0; q < 4; ++q) {
        int row = crow + mi * 16 + q;
        size_t idx = (size_t)row * N + col;
        float val = acc[mi][ni][q] + bv;
        if (outF) atomicAdd(outF + idx, val);
        else      outB[idx] = f2bf(val);
      }
    }
}

// ---------------- swiglu over concatenated FFN-up output ----------------
// hg[m][j] = silu(hcat[m][j]) * hcat[m][3072+j]; 8 elems per thread.
__global__ __launch_bounds__(256) void swiglu_cat(
    const ushort* __restrict__ hcat, ushort* __restrict__ hg, int n8) {
  int i = blockIdx.x * blockDim.x + threadIdx.x;
  if (i >= n8) return;
  int m = i / 384, c = i - m * 384;        // 3072/8 = 384 chunks per row
  const ushort* g = hcat + (size_t)m * 6144 + c * 8;
  const ushort* u = g + 3072;
  ushort o[8];
#pragma unroll
  for (int j = 0; j < 8; ++j) {
    float gv = bf2f(g[j]);
    float uv = bf2f(u[j]);
    float s = gv / (1.0f + __expf(-gv));
    o[j] = f2bf(s * uv);
  }
  *(uint4*)(hg + (size_t)m * 3072 + c * 8) = *(const uint4*)o;
}

// ---------------- 3D neighborhood attention: block per (t, h, head) ----------------
__global__ __launch_bounds__(256) void attn_kernel(
    const ushort* __restrict__ qkv, ushort* __restrict__ out) {
  int head = blockIdx.x;
  int h    = blockIdx.y;
  int t    = blockIdx.z;
  int NT = (t + 1) * 5;
  int tid = threadIdx.x;
  int lane = tid & 63, wid = tid >> 6;
  int hstart = h - 2; hstart = hstart < 0 ? 0 : (hstart > 11 ? 11 : hstart);

  __shared__ ushort v_s[320 * 64];
  __shared__ ushort p_c[16][128];
  __shared__ float red_m[4][16], red_s[4][16];

  for (int c = tid; c < NT * 128; c += 256) {
    int j = c >> 3, dc = c & 7;
    int tile = j >> 4;
    int tp = tile / 5, hh = tile - tp * 5;
    int nb = tp * 256 + (hstart + hh) * 16 + (j & 15);
    uint4 v = *(const uint4*)(qkv + (size_t)nb * 2304 + 1536 + head * 64 + dc * 8);
    *(uint4*)(v_s + j * 64 + dc * 8) = v;
  }

  int c16 = lane & 15, kg = lane >> 4;
  const ushort* qp = qkv + (size_t)(t * 256 + h * 16 + c16) * 2304 + head * 64 + kg * 8;
  bf16x8 qa0 = *(const bf16x8*)qp;
  bf16x8 qa1 = *(const bf16x8*)(qp + 32);

  f32x4 acc[5];
#pragma unroll
  for (int s = 0; s < 5; ++s) {
    f32x4 a = {};
    int ti = wid + s * 4;
    if (ti < NT) {
      int tp = ti / 5, hh = ti - tp * 5;
      const ushort* kp = qkv + (size_t)(tp * 256 + (hstart + hh) * 16 + c16) * 2304
                         + 768 + head * 64 + kg * 8;
      bf16x8 b0 = *(const bf16x8*)kp;
      bf16x8 b1 = *(const bf16x8*)(kp + 32);
      a = __builtin_amdgcn_mfma_f32_16x16x32_bf16(qa0, b0, a, 0, 0, 0);
      a = __builtin_amdgcn_mfma_f32_16x16x32_bf16(qa1, b1, a, 0, 0, 0);
    }
    acc[s] = a;
  }

  bool valid[4]; int wst[4];
#pragma unroll
  for (int r = 0; r < 4; ++r) {
    int q = kg * 4 + r;
    int ws = q - 2; ws = ws < 0 ? 0 : (ws > 11 ? 11 : ws);
    wst[r] = ws;
    valid[r] = (c16 >= ws) && (c16 < ws + 5);
  }

  float mloc[4];
#pragma unroll
  for (int r = 0; r < 4; ++r) mloc[r] = -1e30f;
#pragma unroll
  for (int s = 0; s < 5; ++s) {
    if (wid + s * 4 < NT) {
#pragma unroll
      for (int r = 0; r < 4; ++r)
        if (valid[r]) mloc[r] = fmaxf(mloc[r], acc[s][r]);
    }
  }
#pragma unroll
  for (int r = 0; r < 4; ++r)
    for (int off = 8; off; off >>= 1) mloc[r] = fmaxf(mloc[r], __shfl_xor(mloc[r], off, 64));
  if (c16 == 0) {
#pragma unroll
    for (int r = 0; r < 4; ++r) red_m[wid][kg * 4 + r] = mloc[r];
  }
  __syncthreads();

  float mq[4];
#pragma unroll
  for (int r = 0; r < 4; ++r) {
    int q = kg * 4 + r;
    mq[r] = fmaxf(fmaxf(red_m[0][q], red_m[1][q]), fmaxf(red_m[2][q], red_m[3][q]));
  }

  float pv[5][4];
  float ssum[4] = {0.f, 0.f, 0.f, 0.f};
#pragma unroll
  for (int s = 0; s < 5; ++s) {
    bool live = (wid + s * 4 < NT);
#pragma unroll
    for (int r = 0; r < 4; ++r) {
      float p = (live && valid[r]) ? __expf((acc[s][r] - mq[r]) * 0.125f) : 0.0f;
      pv[s][r] = p;
      ssum[r] += p;
    }
  }
#pragma unroll
  for (int r = 0; r < 4; ++r)
    for (int off = 8; off; off >>= 1) ssum[r] += __shfl_xor(ssum[r], off, 64);
  if (c16 == 0) {
#pragma unroll
    for (int r = 0; r < 4; ++r) red_s[wid][kg * 4 + r] = ssum[r];
  }
  __syncthreads();

  float inv[4];
#pragma unroll
  for (int r = 0; r < 4; ++r) {
    int q = kg * 4 + r;
    inv[r] = 1.0f / (red_s[0][q] + red_s[1][q] + red_s[2][q] + red_s[3][q]);
  }

#pragma unroll
  for (int s = 0; s < 5; ++s) {
    int ti = wid + s * 4;
    if (ti < NT) {
      int tp = ti / 5, hh = ti - tp * 5;
#pragma unroll
      for (int r = 0; r < 4; ++r) {
        if (valid[r]) {
          int wc = c16 - wst[r];
          p_c[kg * 4 + r][(tp * 5 + hh) * 5 + wc] = f2bf(pv[s][r] * inv[r]);
        }
      }
    }
  }
  __syncthreads();

  int q  = tid >> 4;
  int dg = tid & 15;
  int ws2 = q - 2; ws2 = ws2 < 0 ? 0 : (ws2 > 11 ? 11 : ws2);
  float ox = 0.f, oy = 0.f, oz = 0.f, ow = 0.f;
  for (int tp = 0; tp <= t; ++tp) {
#pragma unroll
    for (int hh = 0; hh < 5; ++hh) {
      int jbase = tp * 80 + hh * 16 + ws2;
      const ushort* pb = &p_c[q][(tp * 5 + hh) * 5];
#pragma unroll
      for (int ww = 0; ww < 5; ++ww) {
        float p = bf2f(pb[ww]);
        uint2 v = *(const uint2*)(v_s + (jbase + ww) * 64 + dg * 4);
        ox += p * bf2f((ushort)(v.x & 0xffff));
        oy += p * bf2f((ushort)(v.x >> 16));
        oz += p * bf2f((ushort)(v.y & 0xffff));
        ow += p * bf2f((ushort)(v.y >> 16));
      }
    }
  }
  ushort4 ov;
  ov.x = f2bf(ox); ov.y = f2bf(oy); ov.z = f2bf(oz); ov.w = f2bf(ow);
  *(ushort4*)(out + (size_t)(t * 256 + h * 16 + q) * DM + head * 64 + dg * 4) = ov;
}

extern "C" void kernel_launch(void* const* d_in, const int* in_sizes, int n_in,
                              void* d_out, int out_size, void* d_ws, size_t ws_size,
                              hipStream_t stream) {
  const float* x_in    = (const float*)d_in[0];
  const float* norm1_w = (const float*)d_in[4];
  const float* norm2_w = (const float*)d_in[5];
  const float* qkv_w   = (const float*)d_in[6];
  const float* qkv_b   = (const float*)d_in[7];
  const float* out_w   = (const float*)d_in[8];
  const float* out_b   = (const float*)d_in[9];
  const float* w1      = (const float*)d_in[10];
  const float* w3      = (const float*)d_in[11];
  const float* w2      = (const float*)d_in[12];
  const float* fnw     = (const float*)d_in[13];

  char* p = (char*)d_ws;
  auto alloc = [&](size_t bytes) {
    char* r = p;
    p += (bytes + 255) & ~(size_t)255;
    return r;
  };
  ushort* wq_bf = (ushort*)alloc((size_t)2 * 2304 * 768 * 2);
  ushort* wo_bf = (ushort*)alloc((size_t)2 * 768 * 768 * 2);
  ushort* wcat  = (ushort*)alloc((size_t)2 * 6144 * 768 * 2);  // [w1;w3] per layer
  ushort* w2_bf = (ushort*)alloc((size_t)2 * 768 * 3072 * 2);
  float*  x     = (float*)alloc((size_t)NTOK * DM * 4);
  ushort* xn    = (ushort*)alloc((size_t)NTOK * DM * 2);
  ushort* qkvb  = (ushort*)alloc((size_t)NTOK * 2304 * 2);
  ushort* attnb = (ushort*)alloc((size_t)NTOK * DM * 2);
  ushort* hcat  = (ushort*)alloc((size_t)NTOK * 6144 * 2);
  ushort* hg    = (ushort*)alloc((size_t)NTOK * FFD * 2);

  hipMemcpyAsync(x, x_in, (size_t)NTOK * DM * 4, hipMemcpyDeviceToDevice, stream);

  auto cvt = [&](const float* in, ushort* out, size_t n) {
    int n4 = (int)(n / 4);
    int blocks = (n4 + 255) / 256;
    if (blocks > 2048) blocks = 2048;
    cvt_kernel<<<blocks, 256, 0, stream>>>(in, out, n4);
  };
  cvt(qkv_w, wq_bf, (size_t)2 * 2304 * 768);
  cvt(out_w, wo_bf, (size_t)2 * 768 * 768);
  for (int l = 0; l < 2; ++l) {
    cvt(w1 + (size_t)l * 3072 * 768, wcat + (size_t)l * 6144 * 768, (size_t)3072 * 768);
    cvt(w3 + (size_t)l * 3072 * 768, wcat + (size_t)l * 6144 * 768 + (size_t)3072 * 768,
        (size_t)3072 * 768);
  }
  cvt(w2, w2_bf, (size_t)2 * 768 * 3072);

  for (int l = 0; l < 2; ++l) {
    rmsnorm_kernel<<<NTOK, 256, 0, stream>>>(x, norm1_w + l * DM, xn, nullptr);
    // QKV: N=2304, bf16 out + bias, grid 8x36=288
    gemm128<<<dim3(8 * (2304 / 64), 1), 256, 0, stream>>>(
        xn, wq_bf + (size_t)l * 2304 * 768, qkv_b + l * 2304,
        nullptr, qkvb, 2304, 768, 1);
    attn_kernel<<<dim3(NH, 16, 4), 256, 0, stream>>>(qkvb, attnb);
    // out-proj: N=768, S=2, atomicAdd into x (holds resid), +bias
    gemm128<<<dim3(8 * (DM / 64), 2), 256, 0, stream>>>(
        attnb, wo_bf + (size_t)l * 768 * 768, out_b + l * DM,
        x, nullptr, DM, 768, 2);
    rmsnorm_kernel<<<NTOK, 256, 0, stream>>>(x, norm2_w + l * DM, xn, nullptr);
    // FFN-up: one GEMM over [w1;w3], N=6144, bf16 out, grid 8x96=768
    gemm128<<<dim3(8 * (6144 / 64), 1), 256, 0, stream>>>(
        xn, wcat + (size_t)l * 6144 * 768, nullptr,
        nullptr, hcat, 6144, 768, 1);
    swiglu_cat<<<(NTOK * FFD / 8 + 255) / 256, 256, 0, stream>>>(
        hcat, hg, NTOK * FFD / 8);
    // w2: N=768, K=3072, S=2, atomicAdd into x
    gemm128<<<dim3(8 * (DM / 64), 2), 256, 0, stream>>>(
        hg, w2_bf + (size_t)l * 768 * 3072, nullptr,
        x, nullptr, DM, 3072, 2);
  }
  rmsnorm_kernel<<<NTOK, 256, 0, stream>>>(x, fnw, nullptr, (float*)d_out);
}